// Round 23
// baseline (205.341 us; speedup 1.0000x reference)
//
#include <hip/hip_runtime.h>
#include <stdint.h>

// B=4, S=2048, D=1024, H=16, HD=64. All inputs fp32.
// convert(8 floats/thread, uint4 stores)->bf16; fused Q+K+V GEMM (256x128
// macro-tiles, 8 waves, uniform MFMA orientation, V transposed in epilogue,
// natural XCD map); flash attention (8 waves x 64 q-rows; 4-buffer prefetch;
// swap23 K staging -> lane-local PV frags; fixed-max softmax; MFMA
// denominator; XCD swizzle); out-proj GEMM (256x128) fp32.

#define B_ 4
#define S_ 2048
#define D_ 1024
#define H_ 16
#define HD_ 64
#define M_ (B_ * S_)

typedef __bf16 bf16x8 __attribute__((ext_vector_type(8)));
typedef float f32x4 __attribute__((ext_vector_type(4)));
typedef float f32x16 __attribute__((ext_vector_type(16)));
typedef unsigned short u16;
typedef union { bf16x8 v; unsigned u[4]; } bfu;

// 0.125 (1/sqrt(HD)) * log2(e): scores come out in log2 units
#define QSCALE 0.18033688011112042f
#define MFIX 8.0f  // fixed softmax shift (log2 units); scores bounded ~|3|

__device__ __forceinline__ u16 f2bf(float f) {
  union { float f; unsigned u; } v; v.f = f;
  unsigned u = v.u;
  u += 0x7fff + ((u >> 16) & 1);
  return (u16)(u >> 16);
}

__device__ __forceinline__ unsigned packbf2(float a, float b) {
  return (unsigned)f2bf(a) | ((unsigned)f2bf(b) << 16);
}

__device__ __forceinline__ float exp2_fast(float x) {
#if __has_builtin(__builtin_amdgcn_exp2f)
  return __builtin_amdgcn_exp2f(x);
#else
  return __expf(x * 0.69314718056f);
#endif
}

__device__ __forceinline__ unsigned packbf(float a, float b) {
  union { unsigned u; __bf16 h[2]; } v;
  v.h[0] = (__bf16)a; v.h[1] = (__bf16)b;
  return v.u;
}

__device__ __forceinline__ void gl2lds16(const void* g, void* l) {
  __builtin_amdgcn_global_load_lds(
      (const __attribute__((address_space(1))) unsigned int*)g,
      (__attribute__((address_space(3))) unsigned int*)l, 16, 0, 0);
}

// ---------------- convert fp32 -> bf16 (8 floats/thread, uint4 store) --------
__global__ __launch_bounds__(256) void convert_kernel(
    const float* __restrict__ x, const float* __restrict__ wq,
    const float* __restrict__ wk, const float* __restrict__ wv,
    const float* __restrict__ wo, u16* __restrict__ xb, u16* __restrict__ wqb,
    u16* __restrict__ wkb, u16* __restrict__ wvb, u16* __restrict__ wob) {
  const int64_t NX = (int64_t)M_ * D_ / 8;  // 1M groups
  const int64_t NW = (int64_t)D_ * D_ / 8;  // 128K groups
  int64_t i = (int64_t)blockIdx.x * blockDim.x + threadIdx.x;
  const float* src; u16* dst; int64_t off;
  if (i < NX)              { src = x;  dst = xb;  off = i; }
  else if (i < NX + NW)    { src = wq; dst = wqb; off = i - NX; }
  else if (i < NX + 2*NW)  { src = wk; dst = wkb; off = i - NX - NW; }
  else if (i < NX + 3*NW)  { src = wv; dst = wvb; off = i - NX - 2*NW; }
  else                     { src = wo; dst = wob; off = i - NX - 3*NW; }
  const float4* p = reinterpret_cast<const float4*>(src) + off * 2;
  float4 a = p[0], b = p[1];
  uint4 o;
  o.x = packbf2(a.x, a.y); o.y = packbf2(a.z, a.w);
  o.z = packbf2(b.x, b.y); o.w = packbf2(b.z, b.w);
  reinterpret_cast<uint4*>(dst)[off] = o;
}

// ---------------- fused Q+K+V GEMM (256x128 tile, 8 waves) ----------------
// grid (24, 32): widx = x>>3 (0=Q scaled, 1=K, 2=V), col-panel = x&7,
// row0 = y*256. Linear id %8 = x%8 -> XCD hosts Q/K/V panels j (L2-resident).
// Per K-step per wave: 4 A + 2 B gl2lds (vs 8 for 128x128) -> B staging per
// output halves. Wave-tiles: 4x2 grid of 64x64. UNIFORM MFMA orientation;
// V transposed in the epilogue only.
__global__ __launch_bounds__(512) void gemm_qkv_kernel(
    const u16* __restrict__ A, const u16* __restrict__ wqb,
    const u16* __restrict__ wkb, const u16* __restrict__ wvb,
    const float* __restrict__ bq, const float* __restrict__ bk,
    const float* __restrict__ bv, u16* __restrict__ oq, u16* __restrict__ ok,
    u16* __restrict__ ovt) {
  __shared__ u16 As[256 * 64];  // 32KB
  __shared__ u16 Bs[128 * 64];  // 16KB
  const int widx = blockIdx.x >> 3;
  const u16* Bw = (widx == 0) ? wqb : ((widx == 1) ? wkb : wvb);
  const float* bias = (widx == 0) ? bq : ((widx == 1) ? bk : bv);
  const int row0 = blockIdx.y * 256;
  const int col0 = (blockIdx.x & 7) * 128;
  const int tid = threadIdx.x;
  const int lane = tid & 63;
  const int wid = tid >> 6;               // 0..7
  const int wr = (wid >> 1) * 64;         // 0,64,128,192
  const int wc = (wid & 1) * 64;          // 0,64

  f32x4 acc[4][4] = {};
  const int srow = lane >> 3;
  const int cc = (lane & 7) ^ srow;

  for (int kt = 0; kt < D_; kt += 64) {
    __syncthreads();
#pragma unroll
    for (int t = 0; t < 4; ++t) {         // A rows (wid*4+t)*8+srow, 32 groups
      int r = (wid * 4 + t) * 8 + srow;
      gl2lds16(A + (int64_t)(row0 + r) * D_ + kt + cc * 8,
               (char*)As + (wid * 4 + t) * 1024);
    }
#pragma unroll
    for (int t = 0; t < 2; ++t) {         // B rows (wid*2+t)*8+srow, 16 groups
      int r = (wid * 2 + t) * 8 + srow;
      gl2lds16(Bw + (int64_t)(col0 + r) * D_ + kt + cc * 8,
               (char*)Bs + (wid * 2 + t) * 1024);
    }
    __syncthreads();

    bf16x8 af[4][2], bfr[4][2];
#pragma unroll
    for (int mi = 0; mi < 4; ++mi)
#pragma unroll
      for (int ks = 0; ks < 2; ++ks) {
        int c = ks * 4 + (lane >> 4);
        int ra = wr + mi * 16 + (lane & 15);
        af[mi][ks] = *reinterpret_cast<const bf16x8*>(
            (char*)As + ra * 128 + ((c ^ (ra & 7)) << 4));
        int rb = wc + mi * 16 + (lane & 15);
        bfr[mi][ks] = *reinterpret_cast<const bf16x8*>(
            (char*)Bs + rb * 128 + ((c ^ (rb & 7)) << 4));
      }
#pragma unroll
    for (int ks = 0; ks < 2; ++ks)
#pragma unroll
      for (int mi = 0; mi < 4; ++mi)
#pragma unroll
        for (int ni = 0; ni < 4; ++ni)
          acc[mi][ni] = __builtin_amdgcn_mfma_f32_16x16x32_bf16(
              af[mi][ks], bfr[ni][ks], acc[mi][ni], 0, 0, 0);
  }

  if (widx != 2) {
    u16* o = (widx == 0) ? oq : ok;
    const float sc = (widx == 0) ? QSCALE : 1.0f;
#pragma unroll
    for (int mi = 0; mi < 4; ++mi)
#pragma unroll
      for (int ni = 0; ni < 4; ++ni) {
        int j = col0 + wc + ni * 16 + (lane & 15);
        float bvv = bias[j];
        int h = j >> 6, hd = j & 63;
#pragma unroll
        for (int r = 0; r < 4; ++r) {
          int i = row0 + wr + mi * 16 + (lane >> 4) * 4 + r;
          int b = i >> 11, s = i & 2047;
          o[((int64_t)(b * H_ + h) * S_ + s) * HD_ + hd] =
              f2bf((acc[mi][ni][r] + bvv) * sc);
        }
      }
  } else {
    // V^T epilogue: same acc layout, transposed store into [B,H,HD,S].
#pragma unroll
    for (int mi = 0; mi < 4; ++mi)
#pragma unroll
      for (int ni = 0; ni < 4; ++ni) {
        int j = col0 + wc + ni * 16 + (lane & 15);
        float bvv = bias[j];
        int h = j >> 6, hd = j & 63;
#pragma unroll
        for (int r = 0; r < 4; ++r) {
          int i = row0 + wr + mi * 16 + (lane >> 4) * 4 + r;
          int b = i >> 11, s = i & 2047;
          ovt[((int64_t)(b * H_ + h) * HD_ + hd) * S_ + s] =
              f2bf(acc[mi][ni][r] + bvv);
        }
      }
  }
}

// ---------------- out-proj GEMM (256x128 tile, 8 waves, fp32 out) -----------
// grid (8, 32): col0 = x*128 (XCD = x), row0 = y*256.
__global__ __launch_bounds__(512) void gemm_out_kernel(
    const u16* __restrict__ A, const u16* __restrict__ Bw,
    const float* __restrict__ bias, float* __restrict__ out) {
  __shared__ u16 As[256 * 64];
  __shared__ u16 Bs[128 * 64];
  const int row0 = blockIdx.y * 256;
  const int col0 = blockIdx.x * 128;
  const int tid = threadIdx.x;
  const int lane = tid & 63;
  const int wid = tid >> 6;
  const int wr = (wid >> 1) * 64;
  const int wc = (wid & 1) * 64;

  f32x4 acc[4][4] = {};
  const int srow = lane >> 3;
  const int cc = (lane & 7) ^ srow;

  for (int kt = 0; kt < D_; kt += 64) {
    __syncthreads();
#pragma unroll
    for (int t = 0; t < 4; ++t) {
      int r = (wid * 4 + t) * 8 + srow;
      gl2lds16(A + (int64_t)(row0 + r) * D_ + kt + cc * 8,
               (char*)As + (wid * 4 + t) * 1024);
    }
#pragma unroll
    for (int t = 0; t < 2; ++t) {
      int r = (wid * 2 + t) * 8 + srow;
      gl2lds16(Bw + (int64_t)(col0 + r) * D_ + kt + cc * 8,
               (char*)Bs + (wid * 2 + t) * 1024);
    }
    __syncthreads();

    bf16x8 af[4][2], bfr[4][2];
#pragma unroll
    for (int mi = 0; mi < 4; ++mi)
#pragma unroll
      for (int ks = 0; ks < 2; ++ks) {
        int c = ks * 4 + (lane >> 4);
        int ra = wr + mi * 16 + (lane & 15);
        af[mi][ks] = *reinterpret_cast<const bf16x8*>(
            (char*)As + ra * 128 + ((c ^ (ra & 7)) << 4));
        int rb = wc + mi * 16 + (lane & 15);
        bfr[mi][ks] = *reinterpret_cast<const bf16x8*>(
            (char*)Bs + rb * 128 + ((c ^ (rb & 7)) << 4));
      }
#pragma unroll
    for (int ks = 0; ks < 2; ++ks)
#pragma unroll
      for (int mi = 0; mi < 4; ++mi)
#pragma unroll
        for (int ni = 0; ni < 4; ++ni)
          acc[mi][ni] = __builtin_amdgcn_mfma_f32_16x16x32_bf16(
              af[mi][ks], bfr[ni][ks], acc[mi][ni], 0, 0, 0);
  }

#pragma unroll
  for (int mi = 0; mi < 4; ++mi)
#pragma unroll
    for (int ni = 0; ni < 4; ++ni) {
      int j = col0 + wc + ni * 16 + (lane & 15);
      float bvv = bias[j];
#pragma unroll
      for (int r = 0; r < 4; ++r) {
        int i = row0 + wr + mi * 16 + (lane >> 4) * 4 + r;
        out[(int64_t)i * D_ + j] = acc[mi][ni][r] + bvv;
      }
    }
}

// ---------------- flash attention (8 waves x 64 q-rows, 4-buf deep prefetch) --
// grid 256 (XCD-swizzled). One vmcnt(0)+barrier per TWO kv-tiles; loads for
// tiles t+2,t+3 issued after the barrier fly under two tile-computes.
// K staged with swap23 row permutation -> PV A-frags lane-local.
// Softmax: p = exp2(s - 8) (fixed max; scores bounded).
__global__ __launch_bounds__(512, 2) void attn_kernel(
    const u16* __restrict__ Q, const u16* __restrict__ Kg,
    const u16* __restrict__ Vt, u16* __restrict__ AO) {
  __shared__ u16 Ks[4][64 * 64];   // 32KB: swizzled [kv][hd], rows swap23'd
  __shared__ u16 Vs[4][64 * 64];   // 32KB: swizzled [hd][kv], true kv order
  const int tid = threadIdx.x;
  const int lane = tid & 63;
  const int l31 = lane & 31;
  const int hi = lane >> 5;
  const int wid = tid >> 6;        // 0..7
  const int orig = blockIdx.x;     // 256
  const int swz = (orig & 7) * 32 + (orig >> 3);
  const int bh = swz >> 2;
  const int qw = (swz & 3) * 512 + wid * 64;

  // Q as B-operand (32x32x16): qb sub-block q-col = qw + qb*32 + l31
  bf16x8 qf[2][4];
#pragma unroll
  for (int qb = 0; qb < 2; ++qb)
#pragma unroll
    for (int ks = 0; ks < 4; ++ks)
      qf[qb][ks] = *reinterpret_cast<const bf16x8*>(
          Q + ((int64_t)bh * S_ + qw + qb * 32 + l31) * HD_ + ks * 16 + hi * 8);

  bf16x8 ones8;
#pragma unroll
  for (int i = 0; i < 8; ++i) ones8[i] = (__bf16)1.0f;

  f32x16 o0[2] = {}, o1[2] = {}, ls[2] = {};

  const int srow = lane >> 3;
  const int cc = (lane & 7) ^ srow;

  // staging: LDS row lr = wid*8+srow holds global K row swap23(lr); V linear.
  const int lr = wid * 8 + srow;
  const int sr = (lr & ~12) | ((lr & 4) << 1) | ((lr & 8) >> 1);  // swap bits 2,3
  const u16* kp = Kg + ((int64_t)bh * S_ + sr) * HD_ + cc * 8;
  const u16* vp = Vt + ((int64_t)bh * HD_ + lr) * S_ + cc * 8;

  // prologue: stage tiles 0,1 -> bufs 0,1
  gl2lds16(kp, (char*)Ks[0] + wid * 1024); kp += 64 * HD_;
  gl2lds16(vp, (char*)Vs[0] + wid * 1024); vp += 64;
  gl2lds16(kp, (char*)Ks[1] + wid * 1024); kp += 64 * HD_;
  gl2lds16(vp, (char*)Vs[1] + wid * 1024); vp += 64;

  const int NT = S_ / 64;

#define TILE_COMPUTE(KBASE, VBASE)                                             \
  {                                                                            \
    f32x16 sc0[2] = {{}, {}}, sc1[2] = {{}, {}};                               \
    {                                                                          \
      __builtin_amdgcn_s_setprio(1);                                           \
      _Pragma("unroll")                                                        \
      for (int ks = 0; ks < 4; ++ks) {                                         \
        int chunk = 2 * ks + hi;                                               \
        int r0 = l31, r1 = 32 + l31;                                           \
        bf16x8 k0 = *reinterpret_cast<const bf16x8*>(                          \
            (KBASE) + r0 * 128 + ((chunk ^ (r0 & 7)) << 4));                   \
        bf16x8 k1 = *reinterpret_cast<const bf16x8*>(                          \
            (KBASE) + r1 * 128 + ((chunk ^ (r1 & 7)) << 4));                   \
        _Pragma("unroll")                                                      \
        for (int qb = 0; qb < 2; ++qb) {                                       \
          sc0[qb] = __builtin_amdgcn_mfma_f32_32x32x16_bf16(k0, qf[qb][ks],    \
                                                            sc0[qb], 0, 0, 0); \
          sc1[qb] = __builtin_amdgcn_mfma_f32_32x32x16_bf16(k1, qf[qb][ks],    \
                                                            sc1[qb], 0, 0, 0); \
        }                                                                      \
      }                                                                        \
      __builtin_amdgcn_s_setprio(0);                                           \
    }                                                                          \
    bfu pa[2][4];                                                              \
    _Pragma("unroll")                                                          \
    for (int qb = 0; qb < 2; ++qb) {                                           \
      _Pragma("unroll")                                                        \
      for (int tt = 0; tt < 16; ++tt) {                                        \
        sc0[qb][tt] = exp2_fast(sc0[qb][tt] - MFIX);                           \
        sc1[qb][tt] = exp2_fast(sc1[qb][tt] - MFIX);                           \
      }                                                                        \
      _Pragma("unroll")                                                        \
      for (int m = 0; m < 4; ++m) {                                            \
        pa[qb][0].u[m] = packbf(sc0[qb][2 * m], sc0[qb][2 * m + 1]);           \
        pa[qb][1].u[m] = packbf(sc0[qb][8 + 2 * m], sc0[qb][9 + 2 * m]);       \
        pa[qb][2].u[m] = packbf(sc1[qb][2 * m], sc1[qb][2 * m + 1]);           \
        pa[qb][3].u[m] = packbf(sc1[qb][8 + 2 * m], sc1[qb][9 + 2 * m]);       \
      }                                                                        \
    }                                                                          \
    {                                                                          \
      __builtin_amdgcn_s_setprio(1);                                           \
      _Pragma("unroll")                                                        \
      for (int kb = 0; kb < 4; ++kb) {                                         \
        int chunk = 2 * kb + hi;                                               \
        int r0 = l31, r1 = 32 + l31;                                           \
        bf16x8 v0 = *reinterpret_cast<const bf16x8*>(                          \
            (VBASE) + r0 * 128 + ((chunk ^ (r0 & 7)) << 4));                   \
        bf16x8 v1 = *reinterpret_cast<const bf16x8*>(                          \
            (VBASE) + r1 * 128 + ((chunk ^ (r1 & 7)) << 4));                   \
        _Pragma("unroll")                                                      \
        for (int qb = 0; qb < 2; ++qb) {                                       \
          o0[qb] = __builtin_amdgcn_mfma_f32_32x32x16_bf16(pa[qb][kb].v, v0,   \
                                                           o0[qb], 0, 0, 0);   \
          o1[qb] = __builtin_amdgcn_mfma_f32_32x32x16_bf16(pa[qb][kb].v, v1,   \
                                                           o1[qb], 0, 0, 0);   \
          ls[qb] = __builtin_amdgcn_mfma_f32_32x32x16_bf16(pa[qb][kb].v,       \
                                                           ones8, ls[qb],      \
                                                           0, 0, 0);           \
        }                                                                      \
      }                                                                        \
      __builtin_amdgcn_s_setprio(0);                                           \
    }                                                                          \
  }

  for (int t = 0; t < NT; t += 2) {
    asm volatile("s_waitcnt vmcnt(0)" ::: "memory");
    __builtin_amdgcn_s_barrier();
    if (t + 2 < NT) {
      gl2lds16(kp, (char*)Ks[(t + 2) & 3] + wid * 1024); kp += 64 * HD_;
      gl2lds16(vp, (char*)Vs[(t + 2) & 3] + wid * 1024); vp += 64;
      gl2lds16(kp, (char*)Ks[(t + 3) & 3] + wid * 1024); kp += 64 * HD_;
      gl2lds16(vp, (char*)Vs[(t + 3) & 3] + wid * 1024); vp += 64;
    }
    const char* kb0 = (const char*)Ks[t & 3];
    const char* vb0 = (const char*)Vs[t & 3];
    const char* kb1 = (const char*)Ks[(t + 1) & 3];
    const char* vb1 = (const char*)Vs[(t + 1) & 3];
    TILE_COMPUTE(kb0, vb0)
    TILE_COMPUTE(kb1, vb1)
  }
#undef TILE_COMPUTE

  // epilogue: elementwise normalize (ls has o0's exact layout), store
  const int b = bh >> 4, h = bh & 15;
#pragma unroll
  for (int qb = 0; qb < 2; ++qb)
#pragma unroll
    for (int tt = 0; tt < 16; ++tt) {
      int row = (tt & 3) + 8 * (tt >> 2) + 4 * hi;
      float inv = __builtin_amdgcn_rcpf(ls[qb][tt]);
      int qr = qw + qb * 32 + row;
      int64_t base = ((int64_t)(b * S_ + qr)) * D_ + h * HD_ + l31;
      AO[base] = f2bf(o0[qb][tt] * inv);
      AO[base + 32] = f2bf(o1[qb][tt] * inv);
    }
}

extern "C" void kernel_launch(void* const* d_in, const int* in_sizes, int n_in,
                              void* d_out, int out_size, void* d_ws, size_t ws_size,
                              hipStream_t stream) {
  const float* x  = (const float*)d_in[0];
  const float* wq = (const float*)d_in[1];
  const float* bq = (const float*)d_in[2];
  const float* wk = (const float*)d_in[3];
  const float* bk = (const float*)d_in[4];
  const float* wv = (const float*)d_in[5];
  const float* bv = (const float*)d_in[6];
  const float* wo = (const float*)d_in[7];
  const float* bo = (const float*)d_in[8];
  char* ws = (char*)d_ws;
  u16* xb  = (u16*)ws;
  u16* wqb = (u16*)(ws + (16ll << 20));
  u16* wkb = (u16*)(ws + (18ll << 20));
  u16* wvb = (u16*)(ws + (20ll << 20));
  u16* wob = (u16*)(ws + (22ll << 20));
  u16* q   = (u16*)(ws + (24ll << 20));
  u16* k   = (u16*)(ws + (40ll << 20));
  u16* vt  = (u16*)(ws + (56ll << 20));
  u16* ao  = xb;

  convert_kernel<<<6144, 256, 0, stream>>>(x, wq, wk, wv, wo, xb, wqb, wkb, wvb, wob);
  gemm_qkv_kernel<<<dim3(24, 32), 512, 0, stream>>>(xb, wqb, wkb, wvb, bq, bk, bv,
                                                    q, k, vt);
  attn_kernel<<<256, 512, 0, stream>>>(q, k, vt, ao);
  gemm_out_kernel<<<dim3(8, 32), 512, 0, stream>>>(ao, wob, bo, (float*)d_out);
}

// Round 24
// 199.905 us; speedup vs baseline: 1.0272x; 1.0272x over previous
//
#include <hip/hip_runtime.h>
#include <stdint.h>

// B=4, S=2048, D=1024, H=16, HD=64. All inputs fp32.  [R22 best config]
// convert(8 floats/thread, uint4 stores)->bf16; fused Q+K+V GEMM (1536 blocks,
// uniform MFMA orientation — V transposed in the EPILOGUE, no in-loop branch,
// natural XCD map); flash attention (8 waves x 64 q-rows; 4-buffer 2-tile-deep
// prefetch; swap23 K staging -> lane-local PV frags; fixed-max softmax; MFMA
// denominator; XCD swizzle); out-proj GEMM fp32.

#define B_ 4
#define S_ 2048
#define D_ 1024
#define H_ 16
#define HD_ 64
#define M_ (B_ * S_)

typedef __bf16 bf16x8 __attribute__((ext_vector_type(8)));
typedef float f32x4 __attribute__((ext_vector_type(4)));
typedef float f32x16 __attribute__((ext_vector_type(16)));
typedef unsigned short u16;
typedef union { bf16x8 v; unsigned u[4]; } bfu;

// 0.125 (1/sqrt(HD)) * log2(e): scores come out in log2 units
#define QSCALE 0.18033688011112042f
#define MFIX 8.0f  // fixed softmax shift (log2 units); scores bounded ~|3|

__device__ __forceinline__ u16 f2bf(float f) {
  union { float f; unsigned u; } v; v.f = f;
  unsigned u = v.u;
  u += 0x7fff + ((u >> 16) & 1);
  return (u16)(u >> 16);
}

__device__ __forceinline__ unsigned packbf2(float a, float b) {
  return (unsigned)f2bf(a) | ((unsigned)f2bf(b) << 16);
}

__device__ __forceinline__ float exp2_fast(float x) {
#if __has_builtin(__builtin_amdgcn_exp2f)
  return __builtin_amdgcn_exp2f(x);
#else
  return __expf(x * 0.69314718056f);
#endif
}

__device__ __forceinline__ unsigned packbf(float a, float b) {
  union { unsigned u; __bf16 h[2]; } v;
  v.h[0] = (__bf16)a; v.h[1] = (__bf16)b;
  return v.u;
}

__device__ __forceinline__ void gl2lds16(const void* g, void* l) {
  __builtin_amdgcn_global_load_lds(
      (const __attribute__((address_space(1))) unsigned int*)g,
      (__attribute__((address_space(3))) unsigned int*)l, 16, 0, 0);
}

// ---------------- convert fp32 -> bf16 (8 floats/thread, uint4 store) --------
__global__ __launch_bounds__(256) void convert_kernel(
    const float* __restrict__ x, const float* __restrict__ wq,
    const float* __restrict__ wk, const float* __restrict__ wv,
    const float* __restrict__ wo, u16* __restrict__ xb, u16* __restrict__ wqb,
    u16* __restrict__ wkb, u16* __restrict__ wvb, u16* __restrict__ wob) {
  const int64_t NX = (int64_t)M_ * D_ / 8;  // 1M groups
  const int64_t NW = (int64_t)D_ * D_ / 8;  // 128K groups
  int64_t i = (int64_t)blockIdx.x * blockDim.x + threadIdx.x;
  const float* src; u16* dst; int64_t off;
  if (i < NX)              { src = x;  dst = xb;  off = i; }
  else if (i < NX + NW)    { src = wq; dst = wqb; off = i - NX; }
  else if (i < NX + 2*NW)  { src = wk; dst = wkb; off = i - NX - NW; }
  else if (i < NX + 3*NW)  { src = wv; dst = wvb; off = i - NX - 2*NW; }
  else                     { src = wo; dst = wob; off = i - NX - 3*NW; }
  const float4* p = reinterpret_cast<const float4*>(src) + off * 2;
  float4 a = p[0], b = p[1];
  uint4 o;
  o.x = packbf2(a.x, a.y); o.y = packbf2(a.z, a.w);
  o.z = packbf2(b.x, b.y); o.w = packbf2(b.z, b.w);
  reinterpret_cast<uint4*>(dst)[off] = o;
}

// ---------------- fused Q+K+V GEMM ----------------
// grid (24, 64): widx = x>>3 (0=Q scaled, 1=K, 2=V), col-panel = x&7.
// Linear id %8 = x%8 -> XCD hosts Q/K/V panels j (0.75MB, L2-resident).
// 1536 blocks (~5-6/CU TLP). UNIFORM MFMA orientation; V transposed in the
// epilogue only (lane writes 4 consecutive-s u16; quads form 32B segments).
__global__ __launch_bounds__(256) void gemm_qkv_kernel(
    const u16* __restrict__ A, const u16* __restrict__ wqb,
    const u16* __restrict__ wkb, const u16* __restrict__ wvb,
    const float* __restrict__ bq, const float* __restrict__ bk,
    const float* __restrict__ bv, u16* __restrict__ oq, u16* __restrict__ ok,
    u16* __restrict__ ovt) {
  __shared__ u16 As[128 * 64];
  __shared__ u16 Bs[128 * 64];
  const int widx = blockIdx.x >> 3;
  const u16* Bw = (widx == 0) ? wqb : ((widx == 1) ? wkb : wvb);
  const float* bias = (widx == 0) ? bq : ((widx == 1) ? bk : bv);
  const int row0 = blockIdx.y * 128;
  const int col0 = (blockIdx.x & 7) * 128;
  const int tid = threadIdx.x;
  const int lane = tid & 63;
  const int wid = tid >> 6;
  const int wr = (wid >> 1) * 64;
  const int wc = (wid & 1) * 64;

  f32x4 acc[4][4] = {};
  const int srow = lane >> 3;
  const int cc = (lane & 7) ^ srow;

  for (int kt = 0; kt < D_; kt += 64) {
    __syncthreads();
    for (int t = 0; t < 4; ++t) {
      int r = (wid * 4 + t) * 8 + srow;
      gl2lds16(A + (int64_t)(row0 + r) * D_ + kt + cc * 8,
               (char*)As + (wid * 4 + t) * 1024);
      gl2lds16(Bw + (int64_t)(col0 + r) * D_ + kt + cc * 8,
               (char*)Bs + (wid * 4 + t) * 1024);
    }
    __syncthreads();

    bf16x8 af[4][2], bfr[4][2];
#pragma unroll
    for (int mi = 0; mi < 4; ++mi)
#pragma unroll
      for (int ks = 0; ks < 2; ++ks) {
        int c = ks * 4 + (lane >> 4);
        int ra = wr + mi * 16 + (lane & 15);
        af[mi][ks] = *reinterpret_cast<const bf16x8*>(
            (char*)As + ra * 128 + ((c ^ (ra & 7)) << 4));
        int rb = wc + mi * 16 + (lane & 15);
        bfr[mi][ks] = *reinterpret_cast<const bf16x8*>(
            (char*)Bs + rb * 128 + ((c ^ (rb & 7)) << 4));
      }
#pragma unroll
    for (int ks = 0; ks < 2; ++ks)
#pragma unroll
      for (int mi = 0; mi < 4; ++mi)
#pragma unroll
        for (int ni = 0; ni < 4; ++ni)
          acc[mi][ni] = __builtin_amdgcn_mfma_f32_16x16x32_bf16(
              af[mi][ks], bfr[ni][ks], acc[mi][ni], 0, 0, 0);
  }

  if (widx != 2) {
    u16* o = (widx == 0) ? oq : ok;
    const float sc = (widx == 0) ? QSCALE : 1.0f;
#pragma unroll
    for (int mi = 0; mi < 4; ++mi)
#pragma unroll
      for (int ni = 0; ni < 4; ++ni) {
        int j = col0 + wc + ni * 16 + (lane & 15);
        float bvv = bias[j];
        int h = j >> 6, hd = j & 63;
#pragma unroll
        for (int r = 0; r < 4; ++r) {
          int i = row0 + wr + mi * 16 + (lane >> 4) * 4 + r;
          int b = i >> 11, s = i & 2047;
          o[((int64_t)(b * H_ + h) * S_ + s) * HD_ + hd] =
              f2bf((acc[mi][ni][r] + bvv) * sc);
        }
      }
  } else {
    // V^T epilogue: same acc layout, transposed store into [B,H,HD,S].
#pragma unroll
    for (int mi = 0; mi < 4; ++mi)
#pragma unroll
      for (int ni = 0; ni < 4; ++ni) {
        int j = col0 + wc + ni * 16 + (lane & 15);
        float bvv = bias[j];
        int h = j >> 6, hd = j & 63;
#pragma unroll
        for (int r = 0; r < 4; ++r) {
          int i = row0 + wr + mi * 16 + (lane >> 4) * 4 + r;
          int b = i >> 11, s = i & 2047;
          ovt[((int64_t)(b * H_ + h) * HD_ + hd) * S_ + s] =
              f2bf(acc[mi][ni][r] + bvv);
        }
      }
  }
}

// ---------------- out-proj GEMM (fp32 out) ----------------
__global__ __launch_bounds__(256) void gemm_out_kernel(
    const u16* __restrict__ A, const u16* __restrict__ Bw,
    const float* __restrict__ bias, float* __restrict__ out) {
  __shared__ u16 As[128 * 64];
  __shared__ u16 Bs[128 * 64];
  const int tid = threadIdx.x;
  const int lane = tid & 63;
  const int wid = tid >> 6;
  const int row0 = blockIdx.y * 128;
  const int col0 = blockIdx.x * 128;
  const int wr = (wid >> 1) * 64;
  const int wc = (wid & 1) * 64;

  f32x4 acc[4][4] = {};
  const int srow = lane >> 3;
  const int cc = (lane & 7) ^ srow;

  for (int kt = 0; kt < D_; kt += 64) {
    __syncthreads();
    for (int t = 0; t < 4; ++t) {
      int r = (wid * 4 + t) * 8 + srow;
      gl2lds16(A + (int64_t)(row0 + r) * D_ + kt + cc * 8,
               (char*)As + (wid * 4 + t) * 1024);
      gl2lds16(Bw + (int64_t)(col0 + r) * D_ + kt + cc * 8,
               (char*)Bs + (wid * 4 + t) * 1024);
    }
    __syncthreads();

    bf16x8 af[4][2], bfr[4][2];
#pragma unroll
    for (int mi = 0; mi < 4; ++mi)
#pragma unroll
      for (int ks = 0; ks < 2; ++ks) {
        int c = ks * 4 + (lane >> 4);
        int ra = wr + mi * 16 + (lane & 15);
        af[mi][ks] = *reinterpret_cast<const bf16x8*>(
            (char*)As + ra * 128 + ((c ^ (ra & 7)) << 4));
        int rb = wc + mi * 16 + (lane & 15);
        bfr[mi][ks] = *reinterpret_cast<const bf16x8*>(
            (char*)Bs + rb * 128 + ((c ^ (rb & 7)) << 4));
      }
#pragma unroll
    for (int ks = 0; ks < 2; ++ks)
#pragma unroll
      for (int mi = 0; mi < 4; ++mi)
#pragma unroll
        for (int ni = 0; ni < 4; ++ni)
          acc[mi][ni] = __builtin_amdgcn_mfma_f32_16x16x32_bf16(
              af[mi][ks], bfr[ni][ks], acc[mi][ni], 0, 0, 0);
  }

#pragma unroll
  for (int mi = 0; mi < 4; ++mi)
#pragma unroll
    for (int ni = 0; ni < 4; ++ni) {
      int j = col0 + wc + ni * 16 + (lane & 15);
      float bvv = bias[j];
#pragma unroll
      for (int r = 0; r < 4; ++r) {
        int i = row0 + wr + mi * 16 + (lane >> 4) * 4 + r;
        out[(int64_t)i * D_ + j] = acc[mi][ni][r] + bvv;
      }
    }
}

// ---------------- flash attention (8 waves x 64 q-rows, 4-buf deep prefetch) --
// grid 256 (XCD-swizzled). One vmcnt(0)+barrier per TWO kv-tiles; loads for
// tiles t+2,t+3 issued after the barrier fly under two tile-computes.
// K staged with swap23 row permutation -> PV A-frags lane-local.
// Softmax: p = exp2(s - 8) (fixed max; scores bounded).
__global__ __launch_bounds__(512, 2) void attn_kernel(
    const u16* __restrict__ Q, const u16* __restrict__ Kg,
    const u16* __restrict__ Vt, u16* __restrict__ AO) {
  __shared__ u16 Ks[4][64 * 64];   // 32KB: swizzled [kv][hd], rows swap23'd
  __shared__ u16 Vs[4][64 * 64];   // 32KB: swizzled [hd][kv], true kv order
  const int tid = threadIdx.x;
  const int lane = tid & 63;
  const int l31 = lane & 31;
  const int hi = lane >> 5;
  const int wid = tid >> 6;        // 0..7
  const int orig = blockIdx.x;     // 256
  const int swz = (orig & 7) * 32 + (orig >> 3);
  const int bh = swz >> 2;
  const int qw = (swz & 3) * 512 + wid * 64;

  // Q as B-operand (32x32x16): qb sub-block q-col = qw + qb*32 + l31
  bf16x8 qf[2][4];
#pragma unroll
  for (int qb = 0; qb < 2; ++qb)
#pragma unroll
    for (int ks = 0; ks < 4; ++ks)
      qf[qb][ks] = *reinterpret_cast<const bf16x8*>(
          Q + ((int64_t)bh * S_ + qw + qb * 32 + l31) * HD_ + ks * 16 + hi * 8);

  bf16x8 ones8;
#pragma unroll
  for (int i = 0; i < 8; ++i) ones8[i] = (__bf16)1.0f;

  f32x16 o0[2] = {}, o1[2] = {}, ls[2] = {};

  const int srow = lane >> 3;
  const int cc = (lane & 7) ^ srow;

  // staging: LDS row lr = wid*8+srow holds global K row swap23(lr); V linear.
  const int lr = wid * 8 + srow;
  const int sr = (lr & ~12) | ((lr & 4) << 1) | ((lr & 8) >> 1);  // swap bits 2,3
  const u16* kp = Kg + ((int64_t)bh * S_ + sr) * HD_ + cc * 8;
  const u16* vp = Vt + ((int64_t)bh * HD_ + lr) * S_ + cc * 8;

  // prologue: stage tiles 0,1 -> bufs 0,1
  gl2lds16(kp, (char*)Ks[0] + wid * 1024); kp += 64 * HD_;
  gl2lds16(vp, (char*)Vs[0] + wid * 1024); vp += 64;
  gl2lds16(kp, (char*)Ks[1] + wid * 1024); kp += 64 * HD_;
  gl2lds16(vp, (char*)Vs[1] + wid * 1024); vp += 64;

  const int NT = S_ / 64;

#define TILE_COMPUTE(KBASE, VBASE)                                             \
  {                                                                            \
    f32x16 sc0[2] = {{}, {}}, sc1[2] = {{}, {}};                               \
    {                                                                          \
      __builtin_amdgcn_s_setprio(1);                                           \
      _Pragma("unroll")                                                        \
      for (int ks = 0; ks < 4; ++ks) {                                         \
        int chunk = 2 * ks + hi;                                               \
        int r0 = l31, r1 = 32 + l31;                                           \
        bf16x8 k0 = *reinterpret_cast<const bf16x8*>(                          \
            (KBASE) + r0 * 128 + ((chunk ^ (r0 & 7)) << 4));                   \
        bf16x8 k1 = *reinterpret_cast<const bf16x8*>(                          \
            (KBASE) + r1 * 128 + ((chunk ^ (r1 & 7)) << 4));                   \
        _Pragma("unroll")                                                      \
        for (int qb = 0; qb < 2; ++qb) {                                       \
          sc0[qb] = __builtin_amdgcn_mfma_f32_32x32x16_bf16(k0, qf[qb][ks],    \
                                                            sc0[qb], 0, 0, 0); \
          sc1[qb] = __builtin_amdgcn_mfma_f32_32x32x16_bf16(k1, qf[qb][ks],    \
                                                            sc1[qb], 0, 0, 0); \
        }                                                                      \
      }                                                                        \
      __builtin_amdgcn_s_setprio(0);                                           \
    }                                                                          \
    bfu pa[2][4];                                                              \
    _Pragma("unroll")                                                          \
    for (int qb = 0; qb < 2; ++qb) {                                           \
      _Pragma("unroll")                                                        \
      for (int tt = 0; tt < 16; ++tt) {                                        \
        sc0[qb][tt] = exp2_fast(sc0[qb][tt] - MFIX);                           \
        sc1[qb][tt] = exp2_fast(sc1[qb][tt] - MFIX);                           \
      }                                                                        \
      _Pragma("unroll")                                                        \
      for (int m = 0; m < 4; ++m) {                                            \
        pa[qb][0].u[m] = packbf(sc0[qb][2 * m], sc0[qb][2 * m + 1]);           \
        pa[qb][1].u[m] = packbf(sc0[qb][8 + 2 * m], sc0[qb][9 + 2 * m]);       \
        pa[qb][2].u[m] = packbf(sc1[qb][2 * m], sc1[qb][2 * m + 1]);           \
        pa[qb][3].u[m] = packbf(sc1[qb][8 + 2 * m], sc1[qb][9 + 2 * m]);       \
      }                                                                        \
    }                                                                          \
    {                                                                          \
      __builtin_amdgcn_s_setprio(1);                                           \
      _Pragma("unroll")                                                        \
      for (int kb = 0; kb < 4; ++kb) {                                         \
        int chunk = 2 * kb + hi;                                               \
        int r0 = l31, r1 = 32 + l31;                                           \
        bf16x8 v0 = *reinterpret_cast<const bf16x8*>(                          \
            (VBASE) + r0 * 128 + ((chunk ^ (r0 & 7)) << 4));                   \
        bf16x8 v1 = *reinterpret_cast<const bf16x8*>(                          \
            (VBASE) + r1 * 128 + ((chunk ^ (r1 & 7)) << 4));                   \
        _Pragma("unroll")                                                      \
        for (int qb = 0; qb < 2; ++qb) {                                       \
          o0[qb] = __builtin_amdgcn_mfma_f32_32x32x16_bf16(pa[qb][kb].v, v0,   \
                                                           o0[qb], 0, 0, 0);   \
          o1[qb] = __builtin_amdgcn_mfma_f32_32x32x16_bf16(pa[qb][kb].v, v1,   \
                                                           o1[qb], 0, 0, 0);   \
          ls[qb] = __builtin_amdgcn_mfma_f32_32x32x16_bf16(pa[qb][kb].v,       \
                                                           ones8, ls[qb],      \
                                                           0, 0, 0);           \
        }                                                                      \
      }                                                                        \
      __builtin_amdgcn_s_setprio(0);                                           \
    }                                                                          \
  }

  for (int t = 0; t < NT; t += 2) {
    asm volatile("s_waitcnt vmcnt(0)" ::: "memory");
    __builtin_amdgcn_s_barrier();
    if (t + 2 < NT) {
      gl2lds16(kp, (char*)Ks[(t + 2) & 3] + wid * 1024); kp += 64 * HD_;
      gl2lds16(vp, (char*)Vs[(t + 2) & 3] + wid * 1024); vp += 64;
      gl2lds16(kp, (char*)Ks[(t + 3) & 3] + wid * 1024); kp += 64 * HD_;
      gl2lds16(vp, (char*)Vs[(t + 3) & 3] + wid * 1024); vp += 64;
    }
    const char* kb0 = (const char*)Ks[t & 3];
    const char* vb0 = (const char*)Vs[t & 3];
    const char* kb1 = (const char*)Ks[(t + 1) & 3];
    const char* vb1 = (const char*)Vs[(t + 1) & 3];
    TILE_COMPUTE(kb0, vb0)
    TILE_COMPUTE(kb1, vb1)
  }
#undef TILE_COMPUTE

  // epilogue: elementwise normalize (ls has o0's exact layout), store
  const int b = bh >> 4, h = bh & 15;
#pragma unroll
  for (int qb = 0; qb < 2; ++qb)
#pragma unroll
    for (int tt = 0; tt < 16; ++tt) {
      int row = (tt & 3) + 8 * (tt >> 2) + 4 * hi;
      float inv = __builtin_amdgcn_rcpf(ls[qb][tt]);
      int qr = qw + qb * 32 + row;
      int64_t base = ((int64_t)(b * S_ + qr)) * D_ + h * HD_ + l31;
      AO[base] = f2bf(o0[qb][tt] * inv);
      AO[base + 32] = f2bf(o1[qb][tt] * inv);
    }
}

extern "C" void kernel_launch(void* const* d_in, const int* in_sizes, int n_in,
                              void* d_out, int out_size, void* d_ws, size_t ws_size,
                              hipStream_t stream) {
  const float* x  = (const float*)d_in[0];
  const float* wq = (const float*)d_in[1];
  const float* bq = (const float*)d_in[2];
  const float* wk = (const float*)d_in[3];
  const float* bk = (const float*)d_in[4];
  const float* wv = (const float*)d_in[5];
  const float* bv = (const float*)d_in[6];
  const float* wo = (const float*)d_in[7];
  const float* bo = (const float*)d_in[8];
  char* ws = (char*)d_ws;
  u16* xb  = (u16*)ws;
  u16* wqb = (u16*)(ws + (16ll << 20));
  u16* wkb = (u16*)(ws + (18ll << 20));
  u16* wvb = (u16*)(ws + (20ll << 20));
  u16* wob = (u16*)(ws + (22ll << 20));
  u16* q   = (u16*)(ws + (24ll << 20));
  u16* k   = (u16*)(ws + (40ll << 20));
  u16* vt  = (u16*)(ws + (56ll << 20));
  u16* ao  = xb;

  convert_kernel<<<6144, 256, 0, stream>>>(x, wq, wk, wv, wo, xb, wqb, wkb, wvb, wob);
  gemm_qkv_kernel<<<dim3(24, 64), 256, 0, stream>>>(xb, wqb, wkb, wvb, bq, bk, bv,
                                                    q, k, vt);
  attn_kernel<<<256, 512, 0, stream>>>(q, k, vt, ao);
  gemm_out_kernel<<<dim3(8, 64), 256, 0, stream>>>(ao, wob, bo, (float*)d_out);
}